// Round 2
// baseline (1990.083 us; speedup 1.0000x reference)
//
#include <hip/hip_runtime.h>
#include <stdint.h>

typedef unsigned short u16;
using short8  = __attribute__((ext_vector_type(8))) short;
using float4v = __attribute__((ext_vector_type(4))) float;

#define L2E 1.4426950408889634f

__device__ inline float4v f4zero() { float4v z = {0.f, 0.f, 0.f, 0.f}; return z; }

__device__ inline u16 f2bf(float f) {
  union { float f; uint32_t i; } v; v.f = f;
  uint32_t r = v.i + 0x7fffu + ((v.i >> 16) & 1u);
  return (u16)(r >> 16);
}
__device__ inline float bf2f(u16 h) {
  union { uint32_t i; float f; } v; v.i = ((uint32_t)h) << 16; return v.f;
}

// async global->LDS, 16B/lane. LDS dest = wave-uniform base + lane*16 (HW).
__device__ inline void glds16(const u16* g, u16* lds_base, int lane) {
#if __has_builtin(__builtin_amdgcn_global_load_lds)
  (void)lane;
  __builtin_amdgcn_global_load_lds((const __attribute__((address_space(1))) void*)g,
                                   (__attribute__((address_space(3))) void*)lds_base,
                                   16, 0, 0);
#else
  *(uint4*)(lds_base + (size_t)lane * 8) = *(const uint4*)g;
#endif
}

// ---------------------------------------------------------------------------
// fp32 (K,N) row-major -> bf16 (N,K) row-major, per-layer stride out_ls elems.
// grid (N/32, K/32, L), block 256
// ---------------------------------------------------------------------------
__global__ __launch_bounds__(256) void transpose_cast_kernel(
    const float* __restrict__ in, u16* __restrict__ out, int K, int N, size_t out_ls) {
  __shared__ float tile[32][33];
  const int tx = threadIdx.x & 31, ty = threadIdx.x >> 5;
  in  += (size_t)blockIdx.z * K * N;
  out += (size_t)blockIdx.z * out_ls;
  const int n  = blockIdx.x * 32 + tx;
  const int k0 = blockIdx.y * 32;
#pragma unroll
  for (int j = 0; j < 32; j += 8)
    tile[ty + j][tx] = in[(size_t)(k0 + ty + j) * N + n];
  __syncthreads();
  const int k = k0 + tx;
  const int n0 = blockIdx.x * 32;
#pragma unroll
  for (int j = 0; j < 32; j += 8)
    out[(size_t)(n0 + ty + j) * K + k] = f2bf(tile[tx][ty + j]);
}

__global__ __launch_bounds__(256) void cast_kernel(const float* __restrict__ in,
                                                   u16* __restrict__ out) {
  const int i = (blockIdx.x * 256 + threadIdx.x) * 4;
  float4 t = *(const float4*)(in + i);
  ushort4 o;
  o.x = f2bf(t.x); o.y = f2bf(t.y); o.z = f2bf(t.z); o.w = f2bf(t.w);
  *(ushort4*)(out + i) = o;
}

// pb fp32 (1,8,2048,2048) -> pbT bf16 [8][32][2048][64] perm pos=mm*4+nb, *L2E
__global__ __launch_bounds__(256) void pb_tile_kernel(const float* __restrict__ pb,
                                                      u16* __restrict__ pbT) {
  const int g  = blockIdx.x * 256 + threadIdx.x;   // 8,388,608 threads
  const int mm = g & 15;
  const int q  = (g >> 4) & 2047;
  const int kbh = g >> 15;            // kb + 32*h
  const int kb = kbh & 31, h = kbh >> 5;
  const float* src = pb + ((size_t)h * 2048 + q) * 2048 + kb * 64 + mm;
  ushort4 o;
  o.x = f2bf(src[0]  * L2E);
  o.y = f2bf(src[16] * L2E);
  o.z = f2bf(src[32] * L2E);
  o.w = f2bf(src[48] * L2E);
  *(ushort4*)(pbT + ((size_t)(h * 32 + kb) * 2048 + q) * 64 + mm * 4) = o;
}

__global__ __launch_bounds__(256) void maskts_kernel(const float* __restrict__ mask,
                                                     const int* __restrict__ ts,
                                                     float* __restrict__ maskE,
                                                     float* __restrict__ tsf) {
  const int i = blockIdx.x * 256 + threadIdx.x;    // 8192
  maskE[i] = mask[i] * L2E;
  tsf[i]   = (float)ts[i];
}

// ---------------------------------------------------------------------------
// GEMM C[M,N] = A[M,K]*W, W given as Wt (N,K) bf16. BN=128, BK=64, BM template.
// global_load_lds staging with XOR-swizzled 16B chunk placement:
//   chunk c of row r lives at slot (c ^ (r&7)) -> conflict-free b128 frag reads.
// EPI: 2 = fp32 out = acc+bias+bf16 resid; 3 = gelu(acc+bias) bf16;
//      4 = fused QKV scatter (Q,K -> (B,NH,S,DH); V -> (B,NH,DH,S))
// ---------------------------------------------------------------------------
template <int BM, int N, int K, int EPI>
__global__ __launch_bounds__(256) void gemm_kernel(
    const u16* __restrict__ A, const u16* __restrict__ Wt,
    const float* __restrict__ b0, const float* __restrict__ b1, const float* __restrict__ b2,
    const u16* __restrict__ resid,
    void* __restrict__ o0, void* __restrict__ o1, void* __restrict__ o2) {
  constexpr int FI = BM / 32;
  __shared__ __align__(16) u16 As[BM * 64];
  __shared__ __align__(16) u16 Bs[128 * 64];
  const int tid = threadIdx.x, lane = tid & 63, wv = tid >> 6;
  const int quad = lane >> 4, mm = lane & 15;
  const int m0 = blockIdx.x * BM, n0 = blockIdx.y * 128;
  const int wm = (wv >> 1) * (BM / 2), wn = (wv & 1) * 64;
  const int srow = tid >> 3, slot = tid & 7;
  const int chunk = slot ^ (srow & 7);
  const u16* Ag = A  + (size_t)(m0 + srow) * K + chunk * 8;
  const u16* Bg = Wt + (size_t)(n0 + srow) * K + chunk * 8;
  u16* AsW = As + (size_t)(wv * 8) * 64;
  u16* BsW = Bs + (size_t)(wv * 8) * 64;
  const int sw = mm & 7;

  float4v acc[FI][4];
#pragma unroll
  for (int i = 0; i < FI; i++)
#pragma unroll
    for (int j = 0; j < 4; j++) acc[i][j] = f4zero();

  for (int kt = 0; kt < K; kt += 64) {
#pragma unroll
    for (int i = 0; i < FI; i++)
      glds16(Ag + (size_t)i * 32 * K + kt, AsW + i * 32 * 64, lane);
#pragma unroll
    for (int j = 0; j < 4; j++)
      glds16(Bg + (size_t)j * 32 * K + kt, BsW + j * 32 * 64, lane);
    __syncthreads();
#pragma unroll
    for (int ks = 0; ks < 2; ks++) {
      short8 a[FI], b[4];
#pragma unroll
      for (int i = 0; i < FI; i++)
        a[i] = *(const short8*)(As + (size_t)(wm + i * 16 + mm) * 64 + (size_t)((ks * 4 + quad) ^ sw) * 8);
#pragma unroll
      for (int j = 0; j < 4; j++)
        b[j] = *(const short8*)(Bs + (size_t)(wn + j * 16 + mm) * 64 + (size_t)((ks * 4 + quad) ^ sw) * 8);
#pragma unroll
      for (int i = 0; i < FI; i++)
#pragma unroll
        for (int j = 0; j < 4; j++)
          acc[i][j] = __builtin_amdgcn_mfma_f32_16x16x32_bf16(a[i], b[j], acc[i][j], 0, 0, 0);
    }
    __syncthreads();
  }

#pragma unroll
  for (int j = 0; j < 4; j++) {
    const int gn = n0 + wn + j * 16 + mm;
    if (EPI == 4) {
      const int which = gn >> 9, col = gn & 511, h = (gn >> 6) & 7, d = gn & 63;
      const float* bp = (which == 0) ? b0 : (which == 1) ? b1 : b2;
      const float bias = bp[col];
      u16* dst = (which == 0) ? (u16*)o0 : (which == 1) ? (u16*)o1 : (u16*)o2;
#pragma unroll
      for (int i = 0; i < FI; i++)
#pragma unroll
        for (int r = 0; r < 4; r++) {
          const int gm = m0 + wm + i * 16 + quad * 4 + r;
          const int b_ = gm >> 11, s_ = gm & 2047;
          const float val = acc[i][j][r] + bias;
          if (which < 2)
            dst[((size_t)((b_ * 8 + h) * 2048 + s_)) * 64 + d] = f2bf(val);
          else
            dst[((size_t)((b_ * 8 + h) * 64 + d)) * 2048 + s_] = f2bf(val);
        }
    } else {
      const float bias = b0[gn];
#pragma unroll
      for (int i = 0; i < FI; i++)
#pragma unroll
        for (int r = 0; r < 4; r++) {
          const int gm = m0 + wm + i * 16 + quad * 4 + r;
          const float val = acc[i][j][r] + bias;
          const size_t idx = (size_t)gm * N + gn;
          if (EPI == 2) {
            ((float*)o0)[idx] = val + bf2f(resid[idx]);
          } else {  // EPI == 3: exact-erf GELU -> bf16
            const float z  = val * 0.70710678118654752f;
            const float az = fabsf(z);
            const float t  = __builtin_amdgcn_rcpf(1.0f + 0.3275911f * az);
            const float poly = t * (0.254829592f + t * (-0.284496736f +
                               t * (1.421413741f + t * (-1.453152027f + t * 1.061405429f))));
            const float e = __builtin_amdgcn_exp2f(-az * az * L2E);
            float erf_ = 1.0f - poly * e;
            erf_ = (z < 0.0f) ? -erf_ : erf_;
            ((u16*)o0)[idx] = f2bf(val * 0.5f * (1.0f + erf_));
          }
        }
    }
  }
}

// ---------------------------------------------------------------------------
// Flash attention v2: no max-tracking (scores bounded ~O(1)), deferred row-sum.
// grid (S/64, B*NH), block 256 (4 waves x 16 q-rows). Q,K (B,NH,S,DH) bf16,
// V (B,NH,DH,S) bf16, pbT bf16 tiled (*L2E), maskE/tsf f32. ctx (B,S,H) bf16.
// ---------------------------------------------------------------------------
template <bool TILED>
__global__ __launch_bounds__(256) void flash2_kernel(
    const u16* __restrict__ Q, const u16* __restrict__ Kb, const u16* __restrict__ Vt,
    const u16* __restrict__ pbT, const float* __restrict__ pb32,
    const float* __restrict__ maskE, const float* __restrict__ tsf,
    u16* __restrict__ ctx) {
  __shared__ __align__(16) u16 P_lds[4][16][80];
  const int tid = threadIdx.x, lane = tid & 63, w = tid >> 6;
  const int quad = lane >> 4, mm = lane & 15;
  const int bh = blockIdx.y, b_ = bh >> 3, h_ = bh & 7;
  const int q0 = blockIdx.x * 64 + w * 16;
  const size_t qk_base = (size_t)bh * 2048 * 64;

  short8 aq[2];
#pragma unroll
  for (int t = 0; t < 2; t++)
    aq[t] = *(const short8*)(Q + qk_base + (size_t)(q0 + mm) * 64 + t * 32 + quad * 8);

  float tqf[4];
#pragma unroll
  for (int r = 0; r < 4; r++) tqf[r] = tsf[b_ * 2048 + q0 + quad * 4 + r];

  float l_r[4] = {0.f, 0.f, 0.f, 0.f};
  float4v o[4];
#pragma unroll
  for (int ob = 0; ob < 4; ob++) o[ob] = f4zero();

  for (int k0 = 0; k0 < 2048; k0 += 64) {
    float4v s[4];
#pragma unroll
    for (int nb = 0; nb < 4; nb++) {
      const short8 bk0 = *(const short8*)(Kb + qk_base + (size_t)(k0 + nb * 16 + mm) * 64 + quad * 8);
      const short8 bk1 = *(const short8*)(Kb + qk_base + (size_t)(k0 + nb * 16 + mm) * 64 + 32 + quad * 8);
      s[nb] = __builtin_amdgcn_mfma_f32_16x16x32_bf16(aq[0], bk0, f4zero(), 0, 0, 0);
      s[nb] = __builtin_amdgcn_mfma_f32_16x16x32_bf16(aq[1], bk1, s[nb], 0, 0, 0);
    }
    float tkf_[4], mk_[4];
#pragma unroll
    for (int nb = 0; nb < 4; nb++) {
      const int kcol = k0 + nb * 16 + mm;
      tkf_[nb] = tsf[b_ * 2048 + kcol];
      mk_[nb]  = maskE[b_ * 2048 + kcol];
    }
    const int kb_i = k0 >> 6;
#pragma unroll
    for (int r = 0; r < 4; r++) {
      const int qrow = q0 + quad * 4 + r;
      float pbv[4];
      if (TILED) {
        const ushort4 t4 = *(const ushort4*)(pbT + ((size_t)(h_ * 32 + kb_i) * 2048 + qrow) * 64 + mm * 4);
        pbv[0] = bf2f(t4.x); pbv[1] = bf2f(t4.y); pbv[2] = bf2f(t4.z); pbv[3] = bf2f(t4.w);
      } else {
#pragma unroll
        for (int nb = 0; nb < 4; nb++)
          pbv[nb] = pb32[((size_t)h_ * 2048 + qrow) * 2048 + k0 + nb * 16 + mm] * L2E;
      }
#pragma unroll
      for (int nb = 0; nb < 4; nb++) {
        const float u = fmaxf(tqf[r] - tkf_[nb], 0.f);
        const float invE = fmaf(u, L2E, 86561.70245333781f) *
                           __builtin_amdgcn_rcpf(fmaf(u, 9.f, 480000.f));
        const float t = fmaf(s[nb][r], invE, pbv[nb] + mk_[nb]);
        const float p = __builtin_amdgcn_exp2f(t);
        l_r[r] += p;
        P_lds[w][quad * 4 + r][nb * 16 + mm] = f2bf(p);
      }
    }
    const short8 ap0 = *(const short8*)(&P_lds[w][mm][quad * 8]);
    const short8 ap1 = *(const short8*)(&P_lds[w][mm][32 + quad * 8]);
    const size_t v_base = (size_t)bh * 64 * 2048;
#pragma unroll
    for (int ob = 0; ob < 4; ob++) {
      const short8 bv0 = *(const short8*)(Vt + v_base + (size_t)(ob * 16 + mm) * 2048 + k0 + quad * 8);
      const short8 bv1 = *(const short8*)(Vt + v_base + (size_t)(ob * 16 + mm) * 2048 + k0 + 32 + quad * 8);
      o[ob] = __builtin_amdgcn_mfma_f32_16x16x32_bf16(ap0, bv0, o[ob], 0, 0, 0);
      o[ob] = __builtin_amdgcn_mfma_f32_16x16x32_bf16(ap1, bv1, o[ob], 0, 0, 0);
    }
  }
#pragma unroll
  for (int r = 0; r < 4; r++) {
    float l = l_r[r];
#pragma unroll
    for (int sh = 1; sh < 16; sh <<= 1) l += __shfl_xor(l, sh, 64);
    const float rl = __builtin_amdgcn_rcpf(l);
    const int qrow = q0 + quad * 4 + r;
#pragma unroll
    for (int ob = 0; ob < 4; ob++)
      ctx[((size_t)b_ * 2048 + qrow) * 512 + h_ * 64 + ob * 16 + mm] = f2bf(o[ob][r] * rl);
  }
}

// ---------------------------------------------------------------------------
// LayerNorm over H=512: 1 wave/row, 4 rows/block. bf16 out always, f32 optional.
// ---------------------------------------------------------------------------
__global__ __launch_bounds__(256) void ln_kernel(
    const float* __restrict__ in, const float* __restrict__ g, const float* __restrict__ bb,
    float* __restrict__ of, u16* __restrict__ obf) {
  const int lane = threadIdx.x & 63, w = threadIdx.x >> 6;
  const int row = blockIdx.x * 4 + w;
  const float* x = in + (size_t)row * 512;
  float v[8];
  const float4 t0 = *(const float4*)(x + lane * 8);
  const float4 t1 = *(const float4*)(x + lane * 8 + 4);
  v[0] = t0.x; v[1] = t0.y; v[2] = t0.z; v[3] = t0.w;
  v[4] = t1.x; v[5] = t1.y; v[6] = t1.z; v[7] = t1.w;
  float s = 0.f;
#pragma unroll
  for (int i = 0; i < 8; i++) s += v[i];
#pragma unroll
  for (int sh = 1; sh < 64; sh <<= 1) s += __shfl_xor(s, sh, 64);
  const float mean = s * (1.0f / 512.0f);
  float sq = 0.f;
#pragma unroll
  for (int i = 0; i < 8; i++) { const float d = v[i] - mean; sq += d * d; }
#pragma unroll
  for (int sh = 1; sh < 64; sh <<= 1) sq += __shfl_xor(sq, sh, 64);
  const float rstd = rsqrtf(sq * (1.0f / 512.0f) + 1e-12f);
#pragma unroll
  for (int i = 0; i < 8; i++) {
    const int col = lane * 8 + i;
    const float y = (v[i] - mean) * rstd * g[col] + bb[col];
    if (of) of[(size_t)row * 512 + col] = y;
    obf[(size_t)row * 512 + col] = f2bf(y);
  }
}

// ---------------------------------------------------------------------------
extern "C" void kernel_launch(void* const* d_in, const int* in_sizes, int n_in,
                              void* d_out, int out_size, void* d_ws, size_t ws_size,
                              hipStream_t stream) {
  const float* x_in = (const float*)d_in[0];
  const float* mask = (const float*)d_in[1];
  const float* pb   = (const float*)d_in[2];
  const int*   ts   = (const int*)d_in[3];
  const float* wq = (const float*)d_in[4];  const float* bq = (const float*)d_in[5];
  const float* wk = (const float*)d_in[6];  const float* bk = (const float*)d_in[7];
  const float* wvp = (const float*)d_in[8]; const float* bv = (const float*)d_in[9];
  const float* wo = (const float*)d_in[10]; const float* bo = (const float*)d_in[11];
  const float* ln1g = (const float*)d_in[12]; const float* ln1b = (const float*)d_in[13];
  const float* wi = (const float*)d_in[14]; const float* bi = (const float*)d_in[15];
  const float* wo2 = (const float*)d_in[16]; const float* bo2 = (const float*)d_in[17];
  const float* ln2g = (const float*)d_in[18]; const float* ln2b = (const float*)d_in[19];

  char* ws = (char*)d_ws;
  const size_t o_wqkv  = 0;          // 6,291,456 B
  const size_t o_woT   = 6291456;    // 2,097,152
  const size_t o_wiT   = 8388608;    // 8,388,608
  const size_t o_wo2T  = 16777216;   // 8,388,608
  const size_t o_maskE = 25165824;   // 32,768
  const size_t o_tsf   = 25198592;   // 32,768
  const size_t o_xbf   = 25231360;   // 8,388,608
  const size_t o_qb    = 33619968;   // 8,388,608  (hb aliases qb..ctx: 33,554,432)
  const size_t o_kb    = 42008576;
  const size_t o_vb    = 50397184;
  const size_t o_ctx   = 58785792;
  const size_t o_attnb = 67174400;   // 8,388,608
  const size_t o_tmp   = 75563008;   // 16,777,216
  const size_t o_pbT   = 92340224;   // 67,108,864
  const bool tiled = ws_size >= (o_pbT + 67108864ull);

  u16*   wqkvT = (u16*)(ws + o_wqkv);
  u16*   woT   = (u16*)(ws + o_woT);
  u16*   wiT   = (u16*)(ws + o_wiT);
  u16*   wo2T  = (u16*)(ws + o_wo2T);
  float* maskE = (float*)(ws + o_maskE);
  float* tsf   = (float*)(ws + o_tsf);
  u16*   xbf   = (u16*)(ws + o_xbf);
  u16*   qb    = (u16*)(ws + o_qb);
  u16*   kb    = (u16*)(ws + o_kb);
  u16*   vb    = (u16*)(ws + o_vb);
  u16*   ctx   = (u16*)(ws + o_ctx);
  u16*   hb    = (u16*)(ws + o_qb);
  u16*   attnb = (u16*)(ws + o_attnb);
  float* tmp   = (float*)(ws + o_tmp);
  u16*   pbT   = (u16*)(ws + o_pbT);

  const dim3 blk(256);
  transpose_cast_kernel<<<dim3(16, 16, 4), blk, 0, stream>>>(wq,  wqkvT,          512, 512, 786432);
  transpose_cast_kernel<<<dim3(16, 16, 4), blk, 0, stream>>>(wk,  wqkvT + 262144, 512, 512, 786432);
  transpose_cast_kernel<<<dim3(16, 16, 4), blk, 0, stream>>>(wvp, wqkvT + 524288, 512, 512, 786432);
  transpose_cast_kernel<<<dim3(16, 16, 4), blk, 0, stream>>>(wo,  woT,  512, 512,  262144);
  transpose_cast_kernel<<<dim3(64, 16, 4), blk, 0, stream>>>(wi,  wiT,  512, 2048, 1048576);
  transpose_cast_kernel<<<dim3(16, 64, 4), blk, 0, stream>>>(wo2, wo2T, 2048, 512, 1048576);
  maskts_kernel<<<32, blk, 0, stream>>>(mask, ts, maskE, tsf);
  cast_kernel<<<4096, blk, 0, stream>>>(x_in, xbf);
  if (tiled) pb_tile_kernel<<<32768, blk, 0, stream>>>(pb, pbT);

  for (int l = 0; l < 4; l++) {
    gemm_kernel<128, 1536, 512, 4><<<dim3(64, 12), blk, 0, stream>>>(
        xbf, wqkvT + (size_t)l * 786432, bq + l * 512, bk + l * 512, bv + l * 512,
        nullptr, qb, kb, vb);
    if (tiled)
      flash2_kernel<true><<<dim3(32, 32), blk, 0, stream>>>(qb, kb, vb, pbT, pb, maskE, tsf, ctx);
    else
      flash2_kernel<false><<<dim3(32, 32), blk, 0, stream>>>(qb, kb, vb, nullptr, pb, maskE, tsf, ctx);
    gemm_kernel<64, 512, 512, 2><<<dim3(128, 4), blk, 0, stream>>>(
        ctx, woT + (size_t)l * 262144, bo + l * 512, nullptr, nullptr, xbf, tmp, nullptr, nullptr);
    ln_kernel<<<2048, blk, 0, stream>>>(tmp, ln1g + l * 512, ln1b + l * 512, nullptr, attnb);
    gemm_kernel<128, 2048, 512, 3><<<dim3(64, 16), blk, 0, stream>>>(
        attnb, wiT + (size_t)l * 1048576, bi + l * 2048, nullptr, nullptr, nullptr,
        hb, nullptr, nullptr);
    gemm_kernel<64, 512, 2048, 2><<<dim3(128, 4), blk, 0, stream>>>(
        hb, wo2T + (size_t)l * 1048576, bo2 + l * 512, nullptr, nullptr, attnb,
        tmp, nullptr, nullptr);
    ln_kernel<<<2048, blk, 0, stream>>>(tmp, ln2g + l * 512, ln2b + l * 512,
                                        (l == 3) ? (float*)d_out : nullptr, xbf);
  }
  (void)in_sizes; (void)n_in; (void)out_size;
}

// Round 4
// 1372.810 us; speedup vs baseline: 1.4496x; 1.4496x over previous
//
#include <hip/hip_runtime.h>
#include <stdint.h>

typedef unsigned short u16;
using short8  = __attribute__((ext_vector_type(8))) short;
using float4v = __attribute__((ext_vector_type(4))) float;

#define L2E 1.4426950408889634f

__device__ inline float4v f4zero() { float4v z = {0.f, 0.f, 0.f, 0.f}; return z; }

__device__ inline u16 f2bf(float f) {
  union { float f; uint32_t i; } v; v.f = f;
  uint32_t r = v.i + 0x7fffu + ((v.i >> 16) & 1u);
  return (u16)(r >> 16);
}
__device__ inline float bf2f(u16 h) {
  union { uint32_t i; float f; } v; v.i = ((uint32_t)h) << 16; return v.f;
}

// async global->LDS, 16B/lane. LDS dest = wave-uniform base + lane*16 (HW).
__device__ inline void glds16(const u16* g, u16* lds_base, int lane) {
#if __has_builtin(__builtin_amdgcn_global_load_lds)
  (void)lane;
  __builtin_amdgcn_global_load_lds((const __attribute__((address_space(1))) void*)g,
                                   (__attribute__((address_space(3))) void*)lds_base,
                                   16, 0, 0);
#else
  *(uint4*)(lds_base + (size_t)lane * 8) = *(const uint4*)g;
#endif
}

// ---------------------------------------------------------------------------
// fp32 (K,N) row-major -> bf16 (N,K) row-major, per-layer stride out_ls elems.
// ---------------------------------------------------------------------------
__global__ __launch_bounds__(256) void transpose_cast_kernel(
    const float* __restrict__ in, u16* __restrict__ out, int K, int N, size_t out_ls) {
  __shared__ float tile[32][33];
  const int tx = threadIdx.x & 31, ty = threadIdx.x >> 5;
  in  += (size_t)blockIdx.z * K * N;
  out += (size_t)blockIdx.z * out_ls;
  const int n  = blockIdx.x * 32 + tx;
  const int k0 = blockIdx.y * 32;
#pragma unroll
  for (int j = 0; j < 32; j += 8)
    tile[ty + j][tx] = in[(size_t)(k0 + ty + j) * N + n];
  __syncthreads();
  const int k = k0 + tx;
  const int n0 = blockIdx.x * 32;
#pragma unroll
  for (int j = 0; j < 32; j += 8)
    out[(size_t)(n0 + ty + j) * K + k] = f2bf(tile[tx][ty + j]);
}

__global__ __launch_bounds__(256) void cast_kernel(const float* __restrict__ in,
                                                   u16* __restrict__ out) {
  const int i = (blockIdx.x * 256 + threadIdx.x) * 4;
  float4 t = *(const float4*)(in + i);
  ushort4 o;
  o.x = f2bf(t.x); o.y = f2bf(t.y); o.z = f2bf(t.z); o.w = f2bf(t.w);
  *(ushort4*)(out + i) = o;
}

// pb fp32 (1,8,2048,2048) -> pbT bf16 [8][32][2048][64] perm pos=mm*4+nb, *L2E
__global__ __launch_bounds__(256) void pb_tile_kernel(const float* __restrict__ pb,
                                                      u16* __restrict__ pbT) {
  const int g  = blockIdx.x * 256 + threadIdx.x;
  const int mm = g & 15;
  const int q  = (g >> 4) & 2047;
  const int kbh = g >> 15;
  const int kb = kbh & 31, h = kbh >> 5;
  const float* src = pb + ((size_t)h * 2048 + q) * 2048 + kb * 64 + mm;
  ushort4 o;
  o.x = f2bf(src[0]  * L2E);
  o.y = f2bf(src[16] * L2E);
  o.z = f2bf(src[32] * L2E);
  o.w = f2bf(src[48] * L2E);
  *(ushort4*)(pbT + ((size_t)(h * 32 + kb) * 2048 + q) * 64 + mm * 4) = o;
}

__global__ __launch_bounds__(256) void maskts_kernel(const float* __restrict__ mask,
                                                     const int* __restrict__ ts,
                                                     float* __restrict__ maskE,
                                                     float* __restrict__ tsf) {
  const int i = blockIdx.x * 256 + threadIdx.x;
  maskE[i] = mask[i] * L2E;
  tsf[i]   = (float)ts[i];
}

// ---------------------------------------------------------------------------
// GEMM C[M,N] = A[M,K]*W, W given as Wt (N,K) bf16. BMxBN tile, BK=64.
// global_load_lds staging, XOR-swizzled chunk placement (conflict-free b128).
// EPI: 2 = fp32 out = acc+bias+bf16 resid; 3 = gelu(acc+bias) bf16;
//      4 = fused QKV scatter (Q,K -> (B,NH,S,DH); V -> (B,NH,DH,S))
// ---------------------------------------------------------------------------
template <int BM, int BN, int NN, int KK, int EPI>
__global__ __launch_bounds__(256) void gemm_kernel(
    const u16* __restrict__ A, const u16* __restrict__ Wt,
    const float* __restrict__ b0, const float* __restrict__ b1, const float* __restrict__ b2,
    const u16* __restrict__ resid,
    void* __restrict__ o0, void* __restrict__ o1, void* __restrict__ o2) {
  constexpr int FI = BM / 32;   // A staging insts / wave
  constexpr int FJB = BN / 32;  // B staging insts / wave
  constexpr int FIW = BM / 32;  // i-frags per wave
  constexpr int FJW = BN / 32;  // j-frags per wave
  __shared__ __align__(16) u16 As[BM * 64];
  __shared__ __align__(16) u16 Bs[BN * 64];
  const int tid = threadIdx.x, lane = tid & 63, wv = tid >> 6;
  const int quad = lane >> 4, mm = lane & 15;
  const int m0 = blockIdx.x * BM, n0 = blockIdx.y * BN;
  const int wm = (wv >> 1) * (BM / 2), wn = (wv & 1) * (BN / 2);
  const int srow = tid >> 3, slot = tid & 7;
  const int chunk = slot ^ (srow & 7);
  const u16* Ag = A  + (size_t)(m0 + srow) * KK + chunk * 8;
  const u16* Bg = Wt + (size_t)(n0 + srow) * KK + chunk * 8;
  u16* AsW = As + (size_t)(wv * 8) * 64;
  u16* BsW = Bs + (size_t)(wv * 8) * 64;
  const int sw = mm & 7;

  float4v acc[FIW][FJW];
#pragma unroll
  for (int i = 0; i < FIW; i++)
#pragma unroll
    for (int j = 0; j < FJW; j++) acc[i][j] = f4zero();

  for (int kt = 0; kt < KK; kt += 64) {
#pragma unroll
    for (int i = 0; i < FI; i++)
      glds16(Ag + (size_t)i * 32 * KK + kt, AsW + i * 32 * 64, lane);
#pragma unroll
    for (int j = 0; j < FJB; j++)
      glds16(Bg + (size_t)j * 32 * KK + kt, BsW + j * 32 * 64, lane);
    __syncthreads();
#pragma unroll
    for (int ks = 0; ks < 2; ks++) {
      short8 a[FIW], b[FJW];
#pragma unroll
      for (int i = 0; i < FIW; i++)
        a[i] = *(const short8*)(As + (size_t)(wm + i * 16 + mm) * 64 + (size_t)((ks * 4 + quad) ^ sw) * 8);
#pragma unroll
      for (int j = 0; j < FJW; j++)
        b[j] = *(const short8*)(Bs + (size_t)(wn + j * 16 + mm) * 64 + (size_t)((ks * 4 + quad) ^ sw) * 8);
#pragma unroll
      for (int i = 0; i < FIW; i++)
#pragma unroll
        for (int j = 0; j < FJW; j++)
          acc[i][j] = __builtin_amdgcn_mfma_f32_16x16x32_bf16(a[i], b[j], acc[i][j], 0, 0, 0);
    }
    __syncthreads();
  }

#pragma unroll
  for (int j = 0; j < FJW; j++) {
    const int gn = n0 + wn + j * 16 + mm;
    if (EPI == 4) {
      const int which = gn >> 9, col = gn & 511, h = (gn >> 6) & 7, d = gn & 63;
      const float* bp = (which == 0) ? b0 : (which == 1) ? b1 : b2;
      const float bias = bp[col];
      u16* dst = (which == 0) ? (u16*)o0 : (which == 1) ? (u16*)o1 : (u16*)o2;
#pragma unroll
      for (int i = 0; i < FIW; i++)
#pragma unroll
        for (int r = 0; r < 4; r++) {
          const int gm = m0 + wm + i * 16 + quad * 4 + r;
          const int b_ = gm >> 11, s_ = gm & 2047;
          const float val = acc[i][j][r] + bias;
          if (which < 2)
            dst[((size_t)((b_ * 8 + h) * 2048 + s_)) * 64 + d] = f2bf(val);
          else
            dst[((size_t)((b_ * 8 + h) * 64 + d)) * 2048 + s_] = f2bf(val);
        }
    } else {
      const float bias = b0[gn];
#pragma unroll
      for (int i = 0; i < FIW; i++)
#pragma unroll
        for (int r = 0; r < 4; r++) {
          const int gm = m0 + wm + i * 16 + quad * 4 + r;
          const float val = acc[i][j][r] + bias;
          const size_t idx = (size_t)gm * NN + gn;
          if (EPI == 2) {
            ((float*)o0)[idx] = val + bf2f(resid[idx]);
          } else {  // EPI == 3: exact-erf GELU -> bf16
            const float z  = val * 0.70710678118654752f;
            const float az = fabsf(z);
            const float t  = __builtin_amdgcn_rcpf(1.0f + 0.3275911f * az);
            const float poly = t * (0.254829592f + t * (-0.284496736f +
                               t * (1.421413741f + t * (-1.453152027f + t * 1.061405429f))));
            const float e = __builtin_amdgcn_exp2f(-az * az * L2E);
            float erf_ = 1.0f - poly * e;
            erf_ = (z < 0.0f) ? -erf_ : erf_;
            ((u16*)o0)[idx] = f2bf(val * 0.5f * (1.0f + erf_));
          }
        }
    }
  }
}

// ---------------------------------------------------------------------------
// Flash v3: block-cooperative LDS staging of K,V tiles (glds16, XOR swizzle),
// register-prefetch of pbT/ts/mask one k-tile ahead. No max-tracking
// (scores O(1)), deferred row-sum. grid (32, 32), block 256 (4 waves x 16 q).
// ---------------------------------------------------------------------------
template <bool TILED>
__global__ __launch_bounds__(256) void flash3_kernel(
    const u16* __restrict__ Q, const u16* __restrict__ Kb, const u16* __restrict__ Vt,
    const u16* __restrict__ pbT, const float* __restrict__ pb32,
    const float* __restrict__ maskE, const float* __restrict__ tsf,
    u16* __restrict__ ctx) {
  __shared__ __align__(16) u16 Kls[64 * 64];
  __shared__ __align__(16) u16 Vls[64 * 64];
  __shared__ __align__(16) u16 P[4][16 * 72];
  const int tid = threadIdx.x, lane = tid & 63, w = tid >> 6;
  const int quad = lane >> 4, mm = lane & 15;
  const int bh = blockIdx.y, b_ = bh >> 3, h_ = bh & 7;
  const int q0 = blockIdx.x * 64 + w * 16;
  const size_t qk_base = (size_t)bh * 2048 * 64;
  const size_t v_base  = (size_t)bh * 64 * 2048;
  const int srow = lane >> 3, slot = lane & 7;
  const int chunk = slot ^ srow;
  const int sw = mm & 7;

  short8 aq[2];
#pragma unroll
  for (int t = 0; t < 2; t++)
    aq[t] = *(const short8*)(Q + qk_base + (size_t)(q0 + mm) * 64 + t * 32 + quad * 8);

  float tqf[4];
#pragma unroll
  for (int r = 0; r < 4; r++) tqf[r] = tsf[b_ * 2048 + q0 + quad * 4 + r];

  float l_r[4] = {0.f, 0.f, 0.f, 0.f};
  float4v o[4];
#pragma unroll
  for (int ob = 0; ob < 4; ob++) o[ob] = f4zero();

  // prefetch tile-0 per-lane softmax operands
  ushort4 pbc[4]; float tkc[4], mkc[4];
  if (TILED) {
#pragma unroll
    for (int r = 0; r < 4; r++)
      pbc[r] = *(const ushort4*)(pbT + ((size_t)(h_ * 32) * 2048 + q0 + quad * 4 + r) * 64 + mm * 4);
  }
#pragma unroll
  for (int nb = 0; nb < 4; nb++) {
    tkc[nb] = tsf[b_ * 2048 + nb * 16 + mm];
    mkc[nb] = maskE[b_ * 2048 + nb * 16 + mm];
  }

  for (int kt = 0; kt < 32; kt++) {
    const int k0 = kt * 64;
    __syncthreads();   // prior iter's LDS readers done
#pragma unroll
    for (int i = 0; i < 2; i++) {
      const int row = w * 16 + i * 8 + srow;
      glds16(Kb + qk_base + (size_t)(k0 + row) * 64 + chunk * 8, Kls + (w * 16 + i * 8) * 64, lane);
      glds16(Vt + v_base + (size_t)row * 2048 + k0 + chunk * 8, Vls + (w * 16 + i * 8) * 64, lane);
    }
    __syncthreads();   // staging drained (vmcnt0 at barrier)

    // QK^T from LDS
    float4v s[4];
#pragma unroll
    for (int nb = 0; nb < 4; nb++) {
      const short8 kf0 = *(const short8*)(Kls + (size_t)(nb * 16 + mm) * 64 + (size_t)(quad ^ sw) * 8);
      const short8 kf1 = *(const short8*)(Kls + (size_t)(nb * 16 + mm) * 64 + (size_t)((4 + quad) ^ sw) * 8);
      s[nb] = __builtin_amdgcn_mfma_f32_16x16x32_bf16(aq[0], kf0, f4zero(), 0, 0, 0);
      s[nb] = __builtin_amdgcn_mfma_f32_16x16x32_bf16(aq[1], kf1, s[nb], 0, 0, 0);
    }

    // prefetch next tile's softmax operands (hides HBM latency of pbT)
    const int kn = (kt < 31) ? kt + 1 : kt;
    ushort4 pbn[4]; float tkn[4], mkn[4];
    if (TILED) {
#pragma unroll
      for (int r = 0; r < 4; r++)
        pbn[r] = *(const ushort4*)(pbT + ((size_t)(h_ * 32 + kn) * 2048 + q0 + quad * 4 + r) * 64 + mm * 4);
    }
#pragma unroll
    for (int nb = 0; nb < 4; nb++) {
      tkn[nb] = tsf[b_ * 2048 + kn * 64 + nb * 16 + mm];
      mkn[nb] = maskE[b_ * 2048 + kn * 64 + nb * 16 + mm];
    }

    // softmax + P write
#pragma unroll
    for (int r = 0; r < 4; r++) {
      float pbv[4];
      if (TILED) {
        pbv[0] = bf2f(pbc[r].x); pbv[1] = bf2f(pbc[r].y);
        pbv[2] = bf2f(pbc[r].z); pbv[3] = bf2f(pbc[r].w);
      } else {
#pragma unroll
        for (int nb = 0; nb < 4; nb++)
          pbv[nb] = pb32[((size_t)h_ * 2048 + q0 + quad * 4 + r) * 2048 + k0 + nb * 16 + mm] * L2E;
      }
#pragma unroll
      for (int nb = 0; nb < 4; nb++) {
        const float u = fmaxf(tqf[r] - tkc[nb], 0.f);
        const float invE = fmaf(u, L2E, 86561.70245333781f) *
                           __builtin_amdgcn_rcpf(fmaf(u, 9.f, 480000.f));
        const float t = fmaf(s[nb][r], invE, pbv[nb] + mkc[nb]);
        const float p = __builtin_amdgcn_exp2f(t);
        l_r[r] += p;
        P[w][(quad * 4 + r) * 72 + nb * 16 + mm] = f2bf(p);
      }
    }

    // PV from LDS (per-wave P, block-shared V)
    const short8 ap0 = *(const short8*)(&P[w][mm * 72 + quad * 8]);
    const short8 ap1 = *(const short8*)(&P[w][mm * 72 + 32 + quad * 8]);
#pragma unroll
    for (int ob = 0; ob < 4; ob++) {
      const short8 vf0 = *(const short8*)(Vls + (size_t)(ob * 16 + mm) * 64 + (size_t)(quad ^ sw) * 8);
      const short8 vf1 = *(const short8*)(Vls + (size_t)(ob * 16 + mm) * 64 + (size_t)((4 + quad) ^ sw) * 8);
      o[ob] = __builtin_amdgcn_mfma_f32_16x16x32_bf16(ap0, vf0, o[ob], 0, 0, 0);
      o[ob] = __builtin_amdgcn_mfma_f32_16x16x32_bf16(ap1, vf1, o[ob], 0, 0, 0);
    }
#pragma unroll
    for (int r = 0; r < 4; r++) pbc[r] = pbn[r];
#pragma unroll
    for (int nb = 0; nb < 4; nb++) { tkc[nb] = tkn[nb]; mkc[nb] = mkn[nb]; }
  }

#pragma unroll
  for (int r = 0; r < 4; r++) {
    float l = l_r[r];
#pragma unroll
    for (int sh = 1; sh < 16; sh <<= 1) l += __shfl_xor(l, sh, 64);  // sum over mm within quad-group
    const float rl = __builtin_amdgcn_rcpf(l);
    const int qrow = q0 + quad * 4 + r;
#pragma unroll
    for (int ob = 0; ob < 4; ob++)
      ctx[((size_t)b_ * 2048 + qrow) * 512 + h_ * 64 + ob * 16 + mm] = f2bf(o[ob][r] * rl);
  }
}

// ---------------------------------------------------------------------------
// LayerNorm over H=512: 1 wave/row, 4 rows/block. bf16 out always, f32 optional.
// ---------------------------------------------------------------------------
__global__ __launch_bounds__(256) void ln_kernel(
    const float* __restrict__ in, const float* __restrict__ g, const float* __restrict__ bb,
    float* __restrict__ of, u16* __restrict__ obf) {
  const int lane = threadIdx.x & 63, w = threadIdx.x >> 6;
  const int row = blockIdx.x * 4 + w;
  const float* x = in + (size_t)row * 512;
  float v[8];
  const float4 t0 = *(const float4*)(x + lane * 8);
  const float4 t1 = *(const float4*)(x + lane * 8 + 4);
  v[0] = t0.x; v[1] = t0.y; v[2] = t0.z; v[3] = t0.w;
  v[4] = t1.x; v[5] = t1.y; v[6] = t1.z; v[7] = t1.w;
  float s = 0.f;
#pragma unroll
  for (int i = 0; i < 8; i++) s += v[i];
#pragma unroll
  for (int sh = 1; sh < 64; sh <<= 1) s += __shfl_xor(s, sh, 64);
  const float mean = s * (1.0f / 512.0f);
  float sq = 0.f;
#pragma unroll
  for (int i = 0; i < 8; i++) { const float d = v[i] - mean; sq += d * d; }
#pragma unroll
  for (int sh = 1; sh < 64; sh <<= 1) sq += __shfl_xor(sq, sh, 64);
  const float rstd = rsqrtf(sq * (1.0f / 512.0f) + 1e-12f);
#pragma unroll
  for (int i = 0; i < 8; i++) {
    const int col = lane * 8 + i;
    const float y = (v[i] - mean) * rstd * g[col] + bb[col];
    if (of) of[(size_t)row * 512 + col] = y;
    obf[(size_t)row * 512 + col] = f2bf(y);
  }
}

// ---------------------------------------------------------------------------
extern "C" void kernel_launch(void* const* d_in, const int* in_sizes, int n_in,
                              void* d_out, int out_size, void* d_ws, size_t ws_size,
                              hipStream_t stream) {
  const float* x_in = (const float*)d_in[0];
  const float* mask = (const float*)d_in[1];
  const float* pb   = (const float*)d_in[2];
  const int*   ts   = (const int*)d_in[3];
  const float* wq = (const float*)d_in[4];  const float* bq = (const float*)d_in[5];
  const float* wk = (const float*)d_in[6];  const float* bk = (const float*)d_in[7];
  const float* wvp = (const float*)d_in[8]; const float* bv = (const float*)d_in[9];
  const float* wo = (const float*)d_in[10]; const float* bo = (const float*)d_in[11];
  const float* ln1g = (const float*)d_in[12]; const float* ln1b = (const float*)d_in[13];
  const float* wi = (const float*)d_in[14]; const float* bi = (const float*)d_in[15];
  const float* wo2 = (const float*)d_in[16]; const float* bo2 = (const float*)d_in[17];
  const float* ln2g = (const float*)d_in[18]; const float* ln2b = (const float*)d_in[19];

  char* ws = (char*)d_ws;
  const size_t o_wqkv  = 0;
  const size_t o_woT   = 6291456;
  const size_t o_wiT   = 8388608;
  const size_t o_wo2T  = 16777216;
  const size_t o_maskE = 25165824;
  const size_t o_tsf   = 25198592;
  const size_t o_xbf   = 25231360;
  const size_t o_qb    = 33619968;
  const size_t o_kb    = 42008576;
  const size_t o_vb    = 50397184;
  const size_t o_ctx   = 58785792;
  const size_t o_attnb = 67174400;
  const size_t o_tmp   = 75563008;
  const size_t o_pbT   = 92340224;
  const bool tiled = ws_size >= (o_pbT + 67108864ull);

  u16*   wqkvT = (u16*)(ws + o_wqkv);
  u16*   woT   = (u16*)(ws + o_woT);
  u16*   wiT   = (u16*)(ws + o_wiT);
  u16*   wo2T  = (u16*)(ws + o_wo2T);
  float* maskE = (float*)(ws + o_maskE);
  float* tsf   = (float*)(ws + o_tsf);
  u16*   xbf   = (u16*)(ws + o_xbf);
  u16*   qb    = (u16*)(ws + o_qb);
  u16*   kb    = (u16*)(ws + o_kb);
  u16*   vb    = (u16*)(ws + o_vb);
  u16*   ctx   = (u16*)(ws + o_ctx);
  u16*   hb    = (u16*)(ws + o_qb);
  u16*   attnb = (u16*)(ws + o_attnb);
  float* tmp   = (float*)(ws + o_tmp);
  u16*   pbT   = (u16*)(ws + o_pbT);

  const dim3 blk(256);
  transpose_cast_kernel<<<dim3(16, 16, 4), blk, 0, stream>>>(wq,  wqkvT,          512, 512, 786432);
  transpose_cast_kernel<<<dim3(16, 16, 4), blk, 0, stream>>>(wk,  wqkvT + 262144, 512, 512, 786432);
  transpose_cast_kernel<<<dim3(16, 16, 4), blk, 0, stream>>>(wvp, wqkvT + 524288, 512, 512, 786432);
  transpose_cast_kernel<<<dim3(16, 16, 4), blk, 0, stream>>>(wo,  woT,  512, 512,  262144);
  transpose_cast_kernel<<<dim3(64, 16, 4), blk, 0, stream>>>(wi,  wiT,  512, 2048, 1048576);
  transpose_cast_kernel<<<dim3(16, 64, 4), blk, 0, stream>>>(wo2, wo2T, 2048, 512, 1048576);
  maskts_kernel<<<32, blk, 0, stream>>>(mask, ts, maskE, tsf);
  cast_kernel<<<4096, blk, 0, stream>>>(x_in, xbf);
  if (tiled) pb_tile_kernel<<<32768, blk, 0, stream>>>(pb, pbT);

  for (int l = 0; l < 4; l++) {
    gemm_kernel<128, 128, 1536, 512, 4><<<dim3(64, 12), blk, 0, stream>>>(
        xbf, wqkvT + (size_t)l * 786432, bq + l * 512, bk + l * 512, bv + l * 512,
        nullptr, qb, kb, vb);
    if (tiled)
      flash3_kernel<true><<<dim3(32, 32), blk, 0, stream>>>(qb, kb, vb, pbT, pb, maskE, tsf, ctx);
    else
      flash3_kernel<false><<<dim3(32, 32), blk, 0, stream>>>(qb, kb, vb, nullptr, pb, maskE, tsf, ctx);
    gemm_kernel<128, 64, 512, 512, 2><<<dim3(64, 8), blk, 0, stream>>>(
        ctx, woT + (size_t)l * 262144, bo + l * 512, nullptr, nullptr, xbf,
        tmp, nullptr, nullptr);
    ln_kernel<<<2048, blk, 0, stream>>>(tmp, ln1g + l * 512, ln1b + l * 512, nullptr, attnb);
    gemm_kernel<128, 128, 2048, 512, 3><<<dim3(64, 16), blk, 0, stream>>>(
        attnb, wiT + (size_t)l * 1048576, bi + l * 2048, nullptr, nullptr, nullptr,
        hb, nullptr, nullptr);
    gemm_kernel<128, 64, 512, 2048, 2><<<dim3(64, 8), blk, 0, stream>>>(
        hb, wo2T + (size_t)l * 1048576, bo2 + l * 512, nullptr, nullptr, attnb,
        tmp, nullptr, nullptr);
    ln_kernel<<<2048, blk, 0, stream>>>(tmp, ln2g + l * 512, ln2b + l * 512,
                                        (l == 3) ? (float*)d_out : nullptr, xbf);
  }
  (void)in_sizes; (void)n_in; (void)out_size;
}

// Round 5
// 1368.144 us; speedup vs baseline: 1.4546x; 1.0034x over previous
//
#include <hip/hip_runtime.h>
#include <stdint.h>

typedef unsigned short u16;
using half8   = __attribute__((ext_vector_type(8))) _Float16;
using float4v = __attribute__((ext_vector_type(4))) float;

#define L2E 1.4426950408889634f

__device__ inline float4v f4zero() { float4v z = {0.f, 0.f, 0.f, 0.f}; return z; }

__device__ inline u16 f2h(float f) {
  union { _Float16 h; u16 u; } v; v.h = (_Float16)f; return v.u;
}
__device__ inline float h2f(u16 u) {
  union { u16 u; _Float16 h; } v; v.u = u; return (float)v.h;
}

// async global->LDS, 16B/lane. LDS dest = wave-uniform base + lane*16 (HW).
__device__ inline void glds16(const u16* g, u16* lds_base, int lane) {
#if __has_builtin(__builtin_amdgcn_global_load_lds)
  (void)lane;
  __builtin_amdgcn_global_load_lds((const __attribute__((address_space(1))) void*)g,
                                   (__attribute__((address_space(3))) void*)lds_base,
                                   16, 0, 0);
#else
  *(uint4*)(lds_base + (size_t)lane * 8) = *(const uint4*)g;
#endif
}

// ---------------------------------------------------------------------------
// fp32 (K,N) row-major -> f16 (N,K) row-major, per-layer stride out_ls elems.
// ---------------------------------------------------------------------------
__global__ __launch_bounds__(256) void transpose_cast_kernel(
    const float* __restrict__ in, u16* __restrict__ out, int K, int N, size_t out_ls) {
  __shared__ float tile[32][33];
  const int tx = threadIdx.x & 31, ty = threadIdx.x >> 5;
  in  += (size_t)blockIdx.z * K * N;
  out += (size_t)blockIdx.z * out_ls;
  const int n  = blockIdx.x * 32 + tx;
  const int k0 = blockIdx.y * 32;
#pragma unroll
  for (int j = 0; j < 32; j += 8)
    tile[ty + j][tx] = in[(size_t)(k0 + ty + j) * N + n];
  __syncthreads();
  const int k = k0 + tx;
  const int n0 = blockIdx.x * 32;
#pragma unroll
  for (int j = 0; j < 32; j += 8)
    out[(size_t)(n0 + ty + j) * K + k] = f2h(tile[tx][ty + j]);
}

__global__ __launch_bounds__(256) void cast_kernel(const float* __restrict__ in,
                                                   u16* __restrict__ out) {
  const int i = (blockIdx.x * 256 + threadIdx.x) * 4;
  float4 t = *(const float4*)(in + i);
  ushort4 o;
  o.x = f2h(t.x); o.y = f2h(t.y); o.z = f2h(t.z); o.w = f2h(t.w);
  *(ushort4*)(out + i) = o;
}

// pb fp32 (1,8,2048,2048) -> pbT f16 [8][32][2048][64] perm pos=mm*4+nb, *L2E
__global__ __launch_bounds__(256) void pb_tile_kernel(const float* __restrict__ pb,
                                                      u16* __restrict__ pbT) {
  const int g  = blockIdx.x * 256 + threadIdx.x;
  const int mm = g & 15;
  const int q  = (g >> 4) & 2047;
  const int kbh = g >> 15;
  const int kb = kbh & 31, h = kbh >> 5;
  const float* src = pb + ((size_t)h * 2048 + q) * 2048 + kb * 64 + mm;
  ushort4 o;
  o.x = f2h(src[0]  * L2E);
  o.y = f2h(src[16] * L2E);
  o.z = f2h(src[32] * L2E);
  o.w = f2h(src[48] * L2E);
  *(ushort4*)(pbT + ((size_t)(h * 32 + kb) * 2048 + q) * 64 + mm * 4) = o;
}

// lag scale inv (head- and layer-independent) -> invT f16 [4][32][2048][64],
// perm pos=mm*4+nb, with L2E folded in.  inv = (u+60000)/(9u+480000), u>=0.
__global__ __launch_bounds__(256) void inv_tile_kernel(const int* __restrict__ ts,
                                                       u16* __restrict__ invT) {
  const int g  = blockIdx.x * 256 + threadIdx.x;   // 4*32*2048*16 = 2^22
  const int mm = g & 15;
  const int q  = (g >> 4) & 2047;
  const int kb = (g >> 15) & 31;
  const int b  = g >> 20;
  const int tq = ts[b * 2048 + q];
  ushort4 o;
  u16* op = (u16*)&o;
#pragma unroll
  for (int nb = 0; nb < 4; nb++) {
    const int k = kb * 64 + nb * 16 + mm;
    const int du = tq - ts[b * 2048 + k];
    const float u = (du > 0) ? (float)du : 0.f;
    op[nb] = f2h(fmaf(u, L2E, 86561.70245333781f) *
                 __builtin_amdgcn_rcpf(fmaf(u, 9.f, 480000.f)));
  }
  *(ushort4*)(invT + ((size_t)(b * 32 + kb) * 2048 + q) * 64 + mm * 4) = o;
}

__global__ __launch_bounds__(256) void maskts_kernel(const float* __restrict__ mask,
                                                     const int* __restrict__ ts,
                                                     float* __restrict__ maskE,
                                                     float* __restrict__ tsf) {
  const int i = blockIdx.x * 256 + threadIdx.x;
  maskE[i] = mask[i] * L2E;
  tsf[i]   = (float)ts[i];
}

// ---------------------------------------------------------------------------
// GEMM C[M,N] = A[M,K]*W, W given as Wt (N,K) f16. BMxBN tile, BK=64.
// global_load_lds staging, XOR-swizzled chunk placement (conflict-free b128).
// EPI: 2 = fp32 out = acc+bias+f16 resid; 3 = gelu(acc+bias) f16;
//      4 = fused QKV scatter (Q,K -> (B,NH,S,DH); V -> (B,NH,DH,S))
// ---------------------------------------------------------------------------
template <int BM, int BN, int NN, int KK, int EPI>
__global__ __launch_bounds__(256) void gemm_kernel(
    const u16* __restrict__ A, const u16* __restrict__ Wt,
    const float* __restrict__ b0, const float* __restrict__ b1, const float* __restrict__ b2,
    const u16* __restrict__ resid,
    void* __restrict__ o0, void* __restrict__ o1, void* __restrict__ o2) {
  constexpr int FI = BM / 32;
  constexpr int FJB = BN / 32;
  constexpr int FIW = BM / 32;
  constexpr int FJW = BN / 32;
  __shared__ __align__(16) u16 As[BM * 64];
  __shared__ __align__(16) u16 Bs[BN * 64];
  const int tid = threadIdx.x, lane = tid & 63, wv = tid >> 6;
  const int quad = lane >> 4, mm = lane & 15;
  const int m0 = blockIdx.x * BM, n0 = blockIdx.y * BN;
  const int wm = (wv >> 1) * (BM / 2), wn = (wv & 1) * (BN / 2);
  const int srow = tid >> 3, slot = tid & 7;
  const int chunk = slot ^ (srow & 7);
  const u16* Ag = A  + (size_t)(m0 + srow) * KK + chunk * 8;
  const u16* Bg = Wt + (size_t)(n0 + srow) * KK + chunk * 8;
  u16* AsW = As + (size_t)(wv * 8) * 64;
  u16* BsW = Bs + (size_t)(wv * 8) * 64;
  const int sw = mm & 7;

  float4v acc[FIW][FJW];
#pragma unroll
  for (int i = 0; i < FIW; i++)
#pragma unroll
    for (int j = 0; j < FJW; j++) acc[i][j] = f4zero();

  for (int kt = 0; kt < KK; kt += 64) {
#pragma unroll
    for (int i = 0; i < FI; i++)
      glds16(Ag + (size_t)i * 32 * KK + kt, AsW + i * 32 * 64, lane);
#pragma unroll
    for (int j = 0; j < FJB; j++)
      glds16(Bg + (size_t)j * 32 * KK + kt, BsW + j * 32 * 64, lane);
    __syncthreads();
#pragma unroll
    for (int ks = 0; ks < 2; ks++) {
      half8 a[FIW], b[FJW];
#pragma unroll
      for (int i = 0; i < FIW; i++)
        a[i] = *(const half8*)(As + (size_t)(wm + i * 16 + mm) * 64 + (size_t)((ks * 4 + quad) ^ sw) * 8);
#pragma unroll
      for (int j = 0; j < FJW; j++)
        b[j] = *(const half8*)(Bs + (size_t)(wn + j * 16 + mm) * 64 + (size_t)((ks * 4 + quad) ^ sw) * 8);
#pragma unroll
      for (int i = 0; i < FIW; i++)
#pragma unroll
        for (int j = 0; j < FJW; j++)
          acc[i][j] = __builtin_amdgcn_mfma_f32_16x16x32_f16(a[i], b[j], acc[i][j], 0, 0, 0);
    }
    __syncthreads();
  }

#pragma unroll
  for (int j = 0; j < FJW; j++) {
    const int gn = n0 + wn + j * 16 + mm;
    if (EPI == 4) {
      const int which = gn >> 9, col = gn & 511, h = (gn >> 6) & 7, d = gn & 63;
      const float* bp = (which == 0) ? b0 : (which == 1) ? b1 : b2;
      const float bias = bp[col];
      u16* dst = (which == 0) ? (u16*)o0 : (which == 1) ? (u16*)o1 : (u16*)o2;
#pragma unroll
      for (int i = 0; i < FIW; i++)
#pragma unroll
        for (int r = 0; r < 4; r++) {
          const int gm = m0 + wm + i * 16 + quad * 4 + r;
          const int b_ = gm >> 11, s_ = gm & 2047;
          const float val = acc[i][j][r] + bias;
          if (which < 2)
            dst[((size_t)((b_ * 8 + h) * 2048 + s_)) * 64 + d] = f2h(val);
          else
            dst[((size_t)((b_ * 8 + h) * 64 + d)) * 2048 + s_] = f2h(val);
        }
    } else {
      const float bias = b0[gn];
#pragma unroll
      for (int i = 0; i < FIW; i++)
#pragma unroll
        for (int r = 0; r < 4; r++) {
          const int gm = m0 + wm + i * 16 + quad * 4 + r;
          const float val = acc[i][j][r] + bias;
          const size_t idx = (size_t)gm * NN + gn;
          if (EPI == 2) {
            ((float*)o0)[idx] = val + h2f(resid[idx]);
          } else {  // EPI == 3: exact-erf GELU -> f16
            const float z  = val * 0.70710678118654752f;
            const float az = fabsf(z);
            const float t  = __builtin_amdgcn_rcpf(1.0f + 0.3275911f * az);
            const float poly = t * (0.254829592f + t * (-0.284496736f +
                               t * (1.421413741f + t * (-1.453152027f + t * 1.061405429f))));
            const float e = __builtin_amdgcn_exp2f(-az * az * L2E);
            float erf_ = 1.0f - poly * e;
            erf_ = (z < 0.0f) ? -erf_ : erf_;
            ((u16*)o0)[idx] = f2h(val * 0.5f * (1.0f + erf_));
          }
        }
    }
  }
}

// ---------------------------------------------------------------------------
// Flash v4 (f16): LDS-staged K,V (glds16 XOR swizzle); pbT+invT f16 tiled
// operands register-prefetched one k-tile ahead. No max-tracking, deferred
// row-sum. grid (32, 32), block 256 (4 waves x 16 q).
// TILED: 2 = pbT+invT, 1 = pbT only (inv on the fly), 0 = raw pb32.
// ---------------------------------------------------------------------------
template <int TILED>
__global__ __launch_bounds__(256) void flash4_kernel(
    const u16* __restrict__ Q, const u16* __restrict__ Kb, const u16* __restrict__ Vt,
    const u16* __restrict__ pbT, const u16* __restrict__ invT,
    const float* __restrict__ pb32,
    const float* __restrict__ maskE, const float* __restrict__ tsf,
    u16* __restrict__ ctx) {
  __shared__ __align__(16) u16 Kls[64 * 64];
  __shared__ __align__(16) u16 Vls[64 * 64];
  __shared__ __align__(16) u16 P[4][16 * 72];
  const int tid = threadIdx.x, lane = tid & 63, w = tid >> 6;
  const int quad = lane >> 4, mm = lane & 15;
  const int bh = blockIdx.y, b_ = bh >> 3, h_ = bh & 7;
  const int q0 = blockIdx.x * 64 + w * 16;
  const size_t qk_base = (size_t)bh * 2048 * 64;
  const size_t v_base  = (size_t)bh * 64 * 2048;
  const int srow = lane >> 3, slot = lane & 7;
  const int chunk = slot ^ srow;
  const int sw = mm & 7;

  half8 aq[2];
#pragma unroll
  for (int t = 0; t < 2; t++)
    aq[t] = *(const half8*)(Q + qk_base + (size_t)(q0 + mm) * 64 + t * 32 + quad * 8);

  float tqf[4];
  if (TILED < 2) {
#pragma unroll
    for (int r = 0; r < 4; r++) tqf[r] = tsf[b_ * 2048 + q0 + quad * 4 + r];
  }

  float l_r[4] = {0.f, 0.f, 0.f, 0.f};
  float4v o[4];
#pragma unroll
  for (int ob = 0; ob < 4; ob++) o[ob] = f4zero();

  // prefetch tile-0 per-lane softmax operands
  ushort4 pbc[4], invc[4]; float tkc[4], mkc[4];
  if (TILED >= 1) {
#pragma unroll
    for (int r = 0; r < 4; r++)
      pbc[r] = *(const ushort4*)(pbT + ((size_t)(h_ * 32) * 2048 + q0 + quad * 4 + r) * 64 + mm * 4);
  }
  if (TILED == 2) {
#pragma unroll
    for (int r = 0; r < 4; r++)
      invc[r] = *(const ushort4*)(invT + ((size_t)(b_ * 32) * 2048 + q0 + quad * 4 + r) * 64 + mm * 4);
  } else {
#pragma unroll
    for (int nb = 0; nb < 4; nb++) tkc[nb] = tsf[b_ * 2048 + nb * 16 + mm];
  }
#pragma unroll
  for (int nb = 0; nb < 4; nb++) mkc[nb] = maskE[b_ * 2048 + nb * 16 + mm];

  for (int kt = 0; kt < 32; kt++) {
    const int k0 = kt * 64;
    __syncthreads();   // prior iter's LDS readers done
#pragma unroll
    for (int i = 0; i < 2; i++) {
      const int row = w * 16 + i * 8 + srow;
      glds16(Kb + qk_base + (size_t)(k0 + row) * 64 + chunk * 8, Kls + (w * 16 + i * 8) * 64, lane);
      glds16(Vt + v_base + (size_t)row * 2048 + k0 + chunk * 8, Vls + (w * 16 + i * 8) * 64, lane);
    }
    __syncthreads();   // staging drained

    // QK^T from LDS
    float4v s[4];
#pragma unroll
    for (int nb = 0; nb < 4; nb++) {
      const half8 kf0 = *(const half8*)(Kls + (size_t)(nb * 16 + mm) * 64 + (size_t)(quad ^ sw) * 8);
      const half8 kf1 = *(const half8*)(Kls + (size_t)(nb * 16 + mm) * 64 + (size_t)((4 + quad) ^ sw) * 8);
      s[nb] = __builtin_amdgcn_mfma_f32_16x16x32_f16(aq[0], kf0, f4zero(), 0, 0, 0);
      s[nb] = __builtin_amdgcn_mfma_f32_16x16x32_f16(aq[1], kf1, s[nb], 0, 0, 0);
    }

    // prefetch next tile's softmax operands
    const int kn = (kt < 31) ? kt + 1 : kt;
    ushort4 pbn[4], invn[4]; float tkn[4], mkn[4];
    if (TILED >= 1) {
#pragma unroll
      for (int r = 0; r < 4; r++)
        pbn[r] = *(const ushort4*)(pbT + ((size_t)(h_ * 32 + kn) * 2048 + q0 + quad * 4 + r) * 64 + mm * 4);
    }
    if (TILED == 2) {
#pragma unroll
      for (int r = 0; r < 4; r++)
        invn[r] = *(const ushort4*)(invT + ((size_t)(b_ * 32 + kn) * 2048 + q0 + quad * 4 + r) * 64 + mm * 4);
    } else {
#pragma unroll
      for (int nb = 0; nb < 4; nb++) tkn[nb] = tsf[b_ * 2048 + kn * 64 + nb * 16 + mm];
    }
#pragma unroll
    for (int nb = 0; nb < 4; nb++) mkn[nb] = maskE[b_ * 2048 + kn * 64 + nb * 16 + mm];

    // softmax + P write (f16)
#pragma unroll
    for (int r = 0; r < 4; r++) {
      float pbv[4], iv[4];
      if (TILED >= 1) {
        pbv[0] = h2f(pbc[r].x); pbv[1] = h2f(pbc[r].y);
        pbv[2] = h2f(pbc[r].z); pbv[3] = h2f(pbc[r].w);
      } else {
#pragma unroll
        for (int nb = 0; nb < 4; nb++)
          pbv[nb] = pb32[((size_t)h_ * 2048 + q0 + quad * 4 + r) * 2048 + k0 + nb * 16 + mm] * L2E;
      }
      if (TILED == 2) {
        iv[0] = h2f(invc[r].x); iv[1] = h2f(invc[r].y);
        iv[2] = h2f(invc[r].z); iv[3] = h2f(invc[r].w);
      } else {
#pragma unroll
        for (int nb = 0; nb < 4; nb++) {
          const float u = fmaxf(tqf[r] - tkc[nb], 0.f);
          iv[nb] = fmaf(u, L2E, 86561.70245333781f) *
                   __builtin_amdgcn_rcpf(fmaf(u, 9.f, 480000.f));
        }
      }
#pragma unroll
      for (int nb = 0; nb < 4; nb++) {
        const float t = fmaf(s[nb][r], iv[nb], pbv[nb] + mkc[nb]);
        const float p = __builtin_amdgcn_exp2f(t);
        l_r[r] += p;
        P[w][(quad * 4 + r) * 72 + nb * 16 + mm] = f2h(p);
      }
    }

    // PV from LDS
    const half8 ap0 = *(const half8*)(&P[w][mm * 72 + quad * 8]);
    const half8 ap1 = *(const half8*)(&P[w][mm * 72 + 32 + quad * 8]);
#pragma unroll
    for (int ob = 0; ob < 4; ob++) {
      const half8 vf0 = *(const half8*)(Vls + (size_t)(ob * 16 + mm) * 64 + (size_t)(quad ^ sw) * 8);
      const half8 vf1 = *(const half8*)(Vls + (size_t)(ob * 16 + mm) * 64 + (size_t)((4 + quad) ^ sw) * 8);
      o[ob] = __builtin_amdgcn_mfma_f32_16x16x32_f16(ap0, vf0, o[ob], 0, 0, 0);
      o[ob] = __builtin_amdgcn_mfma_f32_16x16x32_f16(ap1, vf1, o[ob], 0, 0, 0);
    }
#pragma unroll
    for (int r = 0; r < 4; r++) { pbc[r] = pbn[r]; invc[r] = invn[r]; }
#pragma unroll
    for (int nb = 0; nb < 4; nb++) { tkc[nb] = tkn[nb]; mkc[nb] = mkn[nb]; }
  }

#pragma unroll
  for (int r = 0; r < 4; r++) {
    float l = l_r[r];
#pragma unroll
    for (int sh = 1; sh < 16; sh <<= 1) l += __shfl_xor(l, sh, 64);  // sum over mm within quad-group
    const float rl = __builtin_amdgcn_rcpf(l);
    const int qrow = q0 + quad * 4 + r;
#pragma unroll
    for (int ob = 0; ob < 4; ob++)
      ctx[((size_t)b_ * 2048 + qrow) * 512 + h_ * 64 + ob * 16 + mm] = f2h(o[ob][r] * rl);
  }
}

// ---------------------------------------------------------------------------
// LayerNorm over H=512: 1 wave/row, 4 rows/block. f16 out always, f32 optional.
// ---------------------------------------------------------------------------
__global__ __launch_bounds__(256) void ln_kernel(
    const float* __restrict__ in, const float* __restrict__ g, const float* __restrict__ bb,
    float* __restrict__ of, u16* __restrict__ obf) {
  const int lane = threadIdx.x & 63, w = threadIdx.x >> 6;
  const int row = blockIdx.x * 4 + w;
  const float* x = in + (size_t)row * 512;
  float v[8];
  const float4 t0 = *(const float4*)(x + lane * 8);
  const float4 t1 = *(const float4*)(x + lane * 8 + 4);
  v[0] = t0.x; v[1] = t0.y; v[2] = t0.z; v[3] = t0.w;
  v[4] = t1.x; v[5] = t1.y; v[6] = t1.z; v[7] = t1.w;
  float s = 0.f;
#pragma unroll
  for (int i = 0; i < 8; i++) s += v[i];
#pragma unroll
  for (int sh = 1; sh < 64; sh <<= 1) s += __shfl_xor(s, sh, 64);
  const float mean = s * (1.0f / 512.0f);
  float sq = 0.f;
#pragma unroll
  for (int i = 0; i < 8; i++) { const float d = v[i] - mean; sq += d * d; }
#pragma unroll
  for (int sh = 1; sh < 64; sh <<= 1) sq += __shfl_xor(sq, sh, 64);
  const float rstd = rsqrtf(sq * (1.0f / 512.0f) + 1e-12f);
#pragma unroll
  for (int i = 0; i < 8; i++) {
    const int col = lane * 8 + i;
    const float y = (v[i] - mean) * rstd * g[col] + bb[col];
    if (of) of[(size_t)row * 512 + col] = y;
    obf[(size_t)row * 512 + col] = f2h(y);
  }
}

// ---------------------------------------------------------------------------
extern "C" void kernel_launch(void* const* d_in, const int* in_sizes, int n_in,
                              void* d_out, int out_size, void* d_ws, size_t ws_size,
                              hipStream_t stream) {
  const float* x_in = (const float*)d_in[0];
  const float* mask = (const float*)d_in[1];
  const float* pb   = (const float*)d_in[2];
  const int*   ts   = (const int*)d_in[3];
  const float* wq = (const float*)d_in[4];  const float* bq = (const float*)d_in[5];
  const float* wk = (const float*)d_in[6];  const float* bk = (const float*)d_in[7];
  const float* wvp = (const float*)d_in[8]; const float* bv = (const float*)d_in[9];
  const float* wo = (const float*)d_in[10]; const float* bo = (const float*)d_in[11];
  const float* ln1g = (const float*)d_in[12]; const float* ln1b = (const float*)d_in[13];
  const float* wi = (const float*)d_in[14]; const float* bi = (const float*)d_in[15];
  const float* wo2 = (const float*)d_in[16]; const float* bo2 = (const float*)d_in[17];
  const float* ln2g = (const float*)d_in[18]; const float* ln2b = (const float*)d_in[19];

  char* ws = (char*)d_ws;
  const size_t o_wqkv  = 0;
  const size_t o_woT   = 6291456;
  const size_t o_wiT   = 8388608;
  const size_t o_wo2T  = 16777216;
  const size_t o_maskE = 25165824;
  const size_t o_tsf   = 25198592;
  const size_t o_xbf   = 25231360;
  const size_t o_qb    = 33619968;
  const size_t o_kb    = 42008576;
  const size_t o_vb    = 50397184;
  const size_t o_ctx   = 58785792;
  const size_t o_attnb = 67174400;
  const size_t o_tmp   = 75563008;
  const size_t o_pbT   = 92340224;    // 67,108,864 B
  const size_t o_invT  = 159449088;   // 33,554,432 B
  const int tiled = (ws_size >= o_invT + 33554432ull) ? 2
                  : (ws_size >= o_pbT + 67108864ull) ? 1 : 0;

  u16*   wqkvT = (u16*)(ws + o_wqkv);
  u16*   woT   = (u16*)(ws + o_woT);
  u16*   wiT   = (u16*)(ws + o_wiT);
  u16*   wo2T  = (u16*)(ws + o_wo2T);
  float* maskE = (float*)(ws + o_maskE);
  float* tsf   = (float*)(ws + o_tsf);
  u16*   xbf   = (u16*)(ws + o_xbf);
  u16*   qb    = (u16*)(ws + o_qb);
  u16*   kb    = (u16*)(ws + o_kb);
  u16*   vb    = (u16*)(ws + o_vb);
  u16*   ctx   = (u16*)(ws + o_ctx);
  u16*   hb    = (u16*)(ws + o_qb);
  u16*   attnb = (u16*)(ws + o_attnb);
  float* tmp   = (float*)(ws + o_tmp);
  u16*   pbT   = (u16*)(ws + o_pbT);
  u16*   invT  = (u16*)(ws + o_invT);

  const dim3 blk(256);
  transpose_cast_kernel<<<dim3(16, 16, 4), blk, 0, stream>>>(wq,  wqkvT,          512, 512, 786432);
  transpose_cast_kernel<<<dim3(16, 16, 4), blk, 0, stream>>>(wk,  wqkvT + 262144, 512, 512, 786432);
  transpose_cast_kernel<<<dim3(16, 16, 4), blk, 0, stream>>>(wvp, wqkvT + 524288, 512, 512, 786432);
  transpose_cast_kernel<<<dim3(16, 16, 4), blk, 0, stream>>>(wo,  woT,  512, 512,  262144);
  transpose_cast_kernel<<<dim3(64, 16, 4), blk, 0, stream>>>(wi,  wiT,  512, 2048, 1048576);
  transpose_cast_kernel<<<dim3(16, 64, 4), blk, 0, stream>>>(wo2, wo2T, 2048, 512, 1048576);
  maskts_kernel<<<32, blk, 0, stream>>>(mask, ts, maskE, tsf);
  cast_kernel<<<4096, blk, 0, stream>>>(x_in, xbf);
  if (tiled >= 1) pb_tile_kernel<<<32768, blk, 0, stream>>>(pb, pbT);
  if (tiled == 2) inv_tile_kernel<<<16384, blk, 0, stream>>>(ts, invT);

  for (int l = 0; l < 4; l++) {
    gemm_kernel<128, 128, 1536, 512, 4><<<dim3(64, 12), blk, 0, stream>>>(
        xbf, wqkvT + (size_t)l * 786432, bq + l * 512, bk + l * 512, bv + l * 512,
        nullptr, qb, kb, vb);
    if (tiled == 2)
      flash4_kernel<2><<<dim3(32, 32), blk, 0, stream>>>(qb, kb, vb, pbT, invT, pb, maskE, tsf, ctx);
    else if (tiled == 1)
      flash4_kernel<1><<<dim3(32, 32), blk, 0, stream>>>(qb, kb, vb, pbT, nullptr, pb, maskE, tsf, ctx);
    else
      flash4_kernel<0><<<dim3(32, 32), blk, 0, stream>>>(qb, kb, vb, nullptr, nullptr, pb, maskE, tsf, ctx);
    gemm_kernel<128, 64, 512, 512, 2><<<dim3(64, 8), blk, 0, stream>>>(
        ctx, woT + (size_t)l * 262144, bo + l * 512, nullptr, nullptr, xbf,
        tmp, nullptr, nullptr);
    ln_kernel<<<2048, blk, 0, stream>>>(tmp, ln1g + l * 512, ln1b + l * 512, nullptr, attnb);
    gemm_kernel<128, 128, 2048, 512, 3><<<dim3(64, 16), blk, 0, stream>>>(
        attnb, wiT + (size_t)l * 1048576, bi + l * 2048, nullptr, nullptr, nullptr,
        hb, nullptr, nullptr);
    gemm_kernel<128, 64, 512, 2048, 2><<<dim3(64, 8), blk, 0, stream>>>(
        hb, wo2T + (size_t)l * 1048576, bo2 + l * 512, nullptr, nullptr, attnb,
        tmp, nullptr, nullptr);
    ln_kernel<<<2048, blk, 0, stream>>>(tmp, ln2g + l * 512, ln2b + l * 512,
                                        (l == 3) ? (float*)d_out : nullptr, xbf);
  }
  (void)in_sizes; (void)n_in; (void)out_size;
}